// Round 2
// baseline (1993.968 us; speedup 1.0000x reference)
//
#include <hip/hip_runtime.h>
#include <hip/hip_bf16.h>
#include <stdint.h>

#define N_TOK 8192
#define DIM   2048
#define FDIM  4096
#define NEXP  8
#define BMN   256
#define HROWS_CAP 18432     // 16384 pairs + 8*255 padding, 256-aligned

// ---- ws layout (bytes) ----
#define XB_OFF   0ull                        // bf16 x  [8192][2048]   33,554,432
#define GH_OFF   33554432ull                 // bf16 G/h [18432][4096] 150,994,944
#define META_OFF 184549376ull
#define CNT_OFF   (META_OFF)                 // int[8]
#define EBASE_OFF (META_OFF + 64ull)         // int[8]
#define ELIST_OFF (META_OFF + 128ull)        // int[8][8192]
#define EWTS_OFF  (ELIST_OFF + 262144ull)    // f32[8][8192]
// end ~185.1 MB  (proven ws >= ~296 MB from round 1)

typedef float f32x4 __attribute__((ext_vector_type(4)));
typedef short s16x8 __attribute__((ext_vector_type(8)));

__device__ __forceinline__ uint32_t pkbf(float a, float b) {
  uint32_t ua = __builtin_bit_cast(uint32_t, a) + 0x8000u;
  uint32_t ub = __builtin_bit_cast(uint32_t, b) + 0x8000u;
  return (ua >> 16) | (ub & 0xffff0000u);
}

__device__ __forceinline__ void gld16(const void* g, void* l) {
  __builtin_amdgcn_global_load_lds(
      (__attribute__((address_space(1))) void*)g,
      (__attribute__((address_space(3))) void*)l, 16, 0, 0);
}

__global__ void zero_out_k(float* out) {
  const size_t i = ((size_t)blockIdx.x * 256 + threadIdx.x) * 4;
  *(float4*)(out + i) = make_float4(0.f, 0.f, 0.f, 0.f);
}

__global__ void init_k(int* cnt) {
  if (threadIdx.x < NEXP) cnt[threadIdx.x] = 0;
}

__global__ void router_k(const float* __restrict__ x, const float* __restrict__ gw,
                         __hip_bfloat16* __restrict__ xb, int* __restrict__ cnt,
                         int* __restrict__ elist, float* __restrict__ ewts) {
  const int n = blockIdx.x;
  const int t = threadIdx.x;
  const float* xr = x + (size_t)n * DIM;
  const float4 v0 = *(const float4*)(xr + t * 8);
  const float4 v1 = *(const float4*)(xr + t * 8 + 4);
  uint4 u;
  u.x = pkbf(v0.x, v0.y); u.y = pkbf(v0.z, v0.w);
  u.z = pkbf(v1.x, v1.y); u.w = pkbf(v1.z, v1.w);
  *(uint4*)(xb + (size_t)n * DIM + t * 8) = u;

  float p[NEXP];
#pragma unroll
  for (int e = 0; e < NEXP; ++e) {
    const float* g = gw + e * DIM + t * 8;
    const float4 g0 = *(const float4*)g;
    const float4 g1 = *(const float4*)(g + 4);
    p[e] = v0.x * g0.x + v0.y * g0.y + v0.z * g0.z + v0.w * g0.w +
           v1.x * g1.x + v1.y * g1.y + v1.z * g1.z + v1.w * g1.w;
  }
#pragma unroll
  for (int off = 32; off >= 1; off >>= 1)
#pragma unroll
    for (int e = 0; e < NEXP; ++e) p[e] += __shfl_xor(p[e], off, 64);

  __shared__ float red[4][NEXP];
  const int lane = t & 63, wv = t >> 6;
  if (lane == 0) {
#pragma unroll
    for (int e = 0; e < NEXP; ++e) red[wv][e] = p[e];
  }
  __syncthreads();
  if (t == 0) {
    float l0 = -1e30f, l1 = -1e30f;
    int e0 = 0, e1 = 0;
#pragma unroll
    for (int e = 0; e < NEXP; ++e) {
      float v = red[0][e] + red[1][e] + red[2][e] + red[3][e];
      if (v > l0) { l1 = l0; e1 = e0; l0 = v; e0 = e; }
      else if (v > l1) { l1 = v; e1 = e; }
    }
    const float ed = expf(l1 - l0);
    const float inv = 1.f / (1.f + ed);
    int s0 = atomicAdd(cnt + e0, 1);
    elist[e0 * N_TOK + s0] = n;
    ewts[e0 * N_TOK + s0] = inv;
    int s1 = atomicAdd(cnt + e1, 1);
    elist[e1 * N_TOK + s1] = (int)((uint32_t)n | 0x80000000u);
    ewts[e1 * N_TOK + s1] = ed * inv;
  }
}

__global__ void scan_k(const int* __restrict__ cnt, int* __restrict__ ebase) {
  if (threadIdx.x == 0 && blockIdx.x == 0) {
    int b = 0;
    for (int e = 0; e < NEXP; ++e) { ebase[e] = b; b += (cnt[e] + 255) & ~255; }
  }
}

// ============================================================================
// 256x256-tile grouped GEMM, BK=64, 8 waves, 4 phases per K-tile.
// MODE 0: C = Xb @ w1^T            -> store bf16 to Gh
// MODE 1: C = Xb @ w3^T            -> h = silu(Gh)*C, store to Gh (in place)
// MODE 2: C = h  @ w2^T            -> atomicAdd(out, we*C)
// A: bf16, staged by global_load_lds (gather via per-lane pre-swizzled source).
// B: fp32, reg-staged (load->cvt->swizzled ds_write), 2-phase lead.
// LDS 128KB: A[2 buf][2 half][128 rows][128B], B same at +64KB.
// Swizzle: granule' = granule ^ (row&7)   (byte ^= (row&7)<<4).
// ============================================================================
template <int KD, int MODE>
__global__ __launch_bounds__(512, 2) void gemm256(
    const __hip_bfloat16* __restrict__ Asrc, const float* __restrict__ Bsrc,
    __hip_bfloat16* __restrict__ Gh, float* __restrict__ out,
    const int* __restrict__ cnt, const int* __restrict__ ebase,
    const int* __restrict__ elist, const float* __restrict__ ewts) {
  constexpr int NT = KD / 64;
  constexpr int NROWS = (MODE == 2 ? DIM : FDIM);  // B rows = output cols
  const int e = blockIdx.z;
  const int count = cnt[e];
  const int mt = blockIdx.y;
  if (mt * BMN >= count) return;
  const int nt = blockIdx.x;
  const int n0 = nt * BMN;

  __shared__ char lds[131072];

  const int tid = threadIdx.x;
  const int lane = tid & 63, wv = tid >> 6;
  const int wr = wv >> 2, wc = wv & 3;
  const int* lst = elist + e * N_TOK;
  const size_t hrow0 = (size_t)ebase[e] + (size_t)mt * BMN;

  // ---- A stage precompute: 4 gld16 per thread per tile (2 halves x 2 chunks)
  const int g_srcA = (lane & 7) ^ (lane >> 3);
  size_t srcAoff[2][2];
  int ldsAoff[2][2];
#pragma unroll
  for (int hf = 0; hf < 2; ++hf)
#pragma unroll
    for (int i = 0; i < 2; ++i) {
      const int r = hf * 128 + (2 * wv + i) * 8 + (lane >> 3);
      size_t grow;
      if (MODE == 2) {
        grow = hrow0 + r;
      } else {
        int idx = mt * BMN + r;
        if (idx >= count) idx = 0;
        grow = (size_t)(lst[idx] & 0x7fffffff);
      }
      srcAoff[hf][i] = grow * (size_t)KD + g_srcA * 8;
      ldsAoff[hf][i] = hf * 16384 + (2 * wv + i) * 1024;
    }

  // ---- B stage precompute: per thread 2 halves x 2 rows, 1 granule each
  const int bg = tid & 7, br = tid >> 3;          // br 0..63
  const int bxor = (bg ^ (br & 7)) << 4;
  const float* srcB[2][2];
  int ldsBoff[2][2];
#pragma unroll
  for (int hf = 0; hf < 2; ++hf)
#pragma unroll
    for (int wh = 0; wh < 2; ++wh) {
      const int rr = hf * 128 + br + wh * 64;
      srcB[hf][wh] = Bsrc + ((size_t)e * NROWS + n0 + rr) * (size_t)KD + bg * 8;
      ldsBoff[hf][wh] = 65536 + hf * 16384 + (br + wh * 64) * 128 + bxor;
    }

  // ---- fragment read offsets
  int frag_off[2];
#pragma unroll
  for (int h = 0; h < 2; ++h)
    frag_off[h] = (lane & 15) * 128 + (((h * 4 + (lane >> 4)) ^ (lane & 7)) << 4);
  const int ardb = wr * 16384;
  const int brdb = 65536 + (wc >> 1) * 16384 + (wc & 1) * 8192;

  f32x4 acc[8][4];
#pragma unroll
  for (int m = 0; m < 8; ++m)
#pragma unroll
    for (int n = 0; n < 4; ++n) acc[m][n] = {0.f, 0.f, 0.f, 0.f};
  s16x8 Bfr[4][2], Afr[2][2];
  float4 ql[2][2][2];

  auto stageA = [&](int t, int nb) {
#pragma unroll
    for (int hf = 0; hf < 2; ++hf)
#pragma unroll
      for (int i = 0; i < 2; ++i)
        gld16(Asrc + srcAoff[hf][i] + t * 64, lds + nb * 32768 + ldsAoff[hf][i]);
  };
  auto loadB = [&](int t) {
#pragma unroll
    for (int hf = 0; hf < 2; ++hf)
#pragma unroll
      for (int wh = 0; wh < 2; ++wh) {
        ql[hf][wh][0] = *(const float4*)(srcB[hf][wh] + t * 64);
        ql[hf][wh][1] = *(const float4*)(srcB[hf][wh] + t * 64 + 4);
      }
  };
  auto writeB = [&](int nb) {
#pragma unroll
    for (int hf = 0; hf < 2; ++hf)
#pragma unroll
      for (int wh = 0; wh < 2; ++wh) {
        uint4 u;
        u.x = pkbf(ql[hf][wh][0].x, ql[hf][wh][0].y);
        u.y = pkbf(ql[hf][wh][0].z, ql[hf][wh][0].w);
        u.z = pkbf(ql[hf][wh][1].x, ql[hf][wh][1].y);
        u.w = pkbf(ql[hf][wh][1].z, ql[hf][wh][1].w);
        *(uint4*)(lds + nb * 32768 + ldsBoff[hf][wh]) = u;
      }
  };
  auto rdB = [&](int nb) {
#pragma unroll
    for (int n = 0; n < 4; ++n)
#pragma unroll
      for (int h = 0; h < 2; ++h)
        Bfr[n][h] = *(const s16x8*)(lds + nb * 32768 + brdb + n * 2048 + frag_off[h]);
  };
  auto rdA = [&](int nb, int m0) {
#pragma unroll
    for (int s = 0; s < 2; ++s)
#pragma unroll
      for (int h = 0; h < 2; ++h)
        Afr[s][h] = *(const s16x8*)(lds + nb * 32768 + ardb + (m0 + s) * 2048 + frag_off[h]);
  };

#define PH_PRE()                                            \
  __builtin_amdgcn_sched_barrier(0);                        \
  __builtin_amdgcn_s_barrier();                             \
  __builtin_amdgcn_sched_barrier(0);                        \
  asm volatile("s_waitcnt lgkmcnt(0)" ::: "memory");        \
  __builtin_amdgcn_sched_barrier(0);                        \
  __builtin_amdgcn_s_setprio(1);

#define PH_POST()                                           \
  __builtin_amdgcn_s_setprio(0);                            \
  __builtin_amdgcn_sched_barrier(0);                        \
  __builtin_amdgcn_s_barrier();                             \
  __builtin_amdgcn_sched_barrier(0);

#define MFMA16(M0)                                                        \
  _Pragma("unroll") for (int h = 0; h < 2; ++h)                           \
  _Pragma("unroll") for (int s = 0; s < 2; ++s)                           \
  _Pragma("unroll") for (int n = 0; n < 4; ++n)                           \
    acc[(M0) + s][n] = __builtin_amdgcn_mfma_f32_16x16x32_bf16(           \
        Afr[s][h], Bfr[n][h], acc[(M0) + s][n], 0, 0, 0);

  // ---- prologue: A(0)->buf0; B(0)->buf0; B(1)->buf1
  stageA(0, 0);
  loadB(0); writeB(0);
  loadB(1); writeB(1);
  asm volatile("s_waitcnt vmcnt(0) lgkmcnt(0)" ::: "memory");
  __builtin_amdgcn_sched_barrier(0);
  __builtin_amdgcn_s_barrier();
  __builtin_amdgcn_sched_barrier(0);

  for (int t = 0; t < NT; ++t) {
    const int nb = t & 1;
    // phase 0: all B-frags + A m0/m1; prefetch A(t+1) -> other buf
    rdB(nb); rdA(nb, 0);
    if (t + 1 < NT) stageA(t + 1, nb ^ 1);
    PH_PRE(); MFMA16(0); PH_POST();
    // phase 1: A m2/m3; issue B(t+2) global loads (into regs)
    rdA(nb, 2);
    if (t + 2 < NT) loadB(t + 2);
    PH_PRE(); MFMA16(2); PH_POST();
    // phase 2: A m4/m5
    rdA(nb, 4);
    PH_PRE(); MFMA16(4); PH_POST();
    // phase 3: A m6/m7; cvt+write B(t+2) into current buf's B region
    rdA(nb, 6);
    if (t + 2 < NT) writeB(nb);
    PH_PRE(); MFMA16(6);
    __builtin_amdgcn_s_setprio(0);
    __builtin_amdgcn_sched_barrier(0);
    asm volatile("s_waitcnt vmcnt(0) lgkmcnt(0)" ::: "memory");
    __builtin_amdgcn_sched_barrier(0);
    __builtin_amdgcn_s_barrier();
    __builtin_amdgcn_sched_barrier(0);
  }

  // ---- epilogue
  const int erow = (lane >> 4) * 4;
  const int ecol = lane & 15;
  if constexpr (MODE == 0) {
#pragma unroll
    for (int m = 0; m < 8; ++m)
#pragma unroll
      for (int n = 0; n < 4; ++n) {
        const size_t cb = n0 + wc * 64 + n * 16 + ecol;
#pragma unroll
        for (int j = 0; j < 4; ++j) {
          const size_t r = hrow0 + wr * 128 + m * 16 + erow + j;
          Gh[r * FDIM + cb] = __float2bfloat16(acc[m][n][j]);
        }
      }
  } else if constexpr (MODE == 1) {
#pragma unroll
    for (int m = 0; m < 8; ++m)
#pragma unroll
      for (int n = 0; n < 4; ++n) {
        const size_t cb = n0 + wc * 64 + n * 16 + ecol;
#pragma unroll
        for (int j = 0; j < 4; ++j) {
          const size_t r = hrow0 + wr * 128 + m * 16 + erow + j;
          const float g = __bfloat162float(Gh[r * FDIM + cb]);
          const float hv = g / (1.f + __expf(-g)) * acc[m][n][j];
          Gh[r * FDIM + cb] = __float2bfloat16(hv);
        }
      }
  } else {
#pragma unroll
    for (int m = 0; m < 8; ++m)
#pragma unroll
      for (int j = 0; j < 4; ++j) {
        const int i = mt * BMN + wr * 128 + m * 16 + erow + j;
        if (i < count) {
          const uint32_t info = (uint32_t)lst[i];
          const int tok = (int)(info & 0x7fffffffu);
          const float wt = ewts[e * N_TOK + i];
          float* prow = out + (size_t)tok * DIM;
#pragma unroll
          for (int n = 0; n < 4; ++n) {
            const int cb = n0 + wc * 64 + n * 16 + ecol;
            atomicAdd(prow + cb, wt * acc[m][n][j]);
          }
        }
      }
  }
}

extern "C" void kernel_launch(void* const* d_in, const int* in_sizes, int n_in,
                              void* d_out, int out_size, void* d_ws, size_t ws_size,
                              hipStream_t stream) {
  const float* stm = (const float*)d_in[0];
  const float* gw = (const float*)d_in[1];
  const float* w1 = (const float*)d_in[2];
  const float* w2 = (const float*)d_in[3];
  const float* w3 = (const float*)d_in[4];
  float* out = (float*)d_out;
  char* ws = (char*)d_ws;

  __hip_bfloat16* xb = (__hip_bfloat16*)(ws + XB_OFF);
  __hip_bfloat16* Gh = (__hip_bfloat16*)(ws + GH_OFF);
  int* cnt = (int*)(ws + CNT_OFF);
  int* ebase = (int*)(ws + EBASE_OFF);
  int* elist = (int*)(ws + ELIST_OFF);
  float* ewts = (float*)(ws + EWTS_OFF);

  zero_out_k<<<N_TOK * DIM / 1024, 256, 0, stream>>>(out);
  init_k<<<1, 64, 0, stream>>>(cnt);
  router_k<<<N_TOK, 256, 0, stream>>>(stm, gw, xb, cnt, elist, ewts);
  scan_k<<<1, 64, 0, stream>>>(cnt, ebase);

  const dim3 gUp(FDIM / BMN, N_TOK / BMN, NEXP);   // (16, 32, 8)
  const dim3 gDn(DIM / BMN, N_TOK / BMN, NEXP);    // (8, 32, 8)

  gemm256<DIM, 0><<<gUp, 512, 0, stream>>>(xb, w1, Gh, out, cnt, ebase, elist, ewts);
  gemm256<DIM, 1><<<gUp, 512, 0, stream>>>(xb, w3, Gh, out, cnt, ebase, elist, ewts);
  gemm256<FDIM, 2><<<gDn, 512, 0, stream>>>(Gh, w2, Gh, out, cnt, ebase, elist, ewts);
}

// Round 3
// 1889.092 us; speedup vs baseline: 1.0555x; 1.0555x over previous
//
#include <hip/hip_runtime.h>
#include <hip/hip_bf16.h>
#include <stdint.h>

#define N_TOK 8192
#define DIM   2048
#define FDIM  4096
#define NEXP  8
#define BMN   256

// ---- ws layout (bytes) ---- (total ~185 MB; round 1 proved ws >= 311 MB)
#define XB_OFF   0ull                        // bf16 x  [8192][2048]   33,554,432
#define GH_OFF   33554432ull                 // bf16 G/h [18432][4096] 150,994,944
#define META_OFF 184549376ull
#define CNT_OFF   (META_OFF)                 // int[8]
#define EBASE_OFF (META_OFF + 64ull)         // int[8]
#define ELIST_OFF (META_OFF + 128ull)        // int[8][8192]
#define EWTS_OFF  (ELIST_OFF + 262144ull)    // f32[8][8192]

typedef float f32x4 __attribute__((ext_vector_type(4)));
typedef short s16x8 __attribute__((ext_vector_type(8)));

__device__ __forceinline__ uint32_t pkbf(float a, float b) {
  uint32_t ua = __builtin_bit_cast(uint32_t, a) + 0x8000u;
  uint32_t ub = __builtin_bit_cast(uint32_t, b) + 0x8000u;
  return (ua >> 16) | (ub & 0xffff0000u);
}

__device__ __forceinline__ void gld16(const void* g, void* l) {
  __builtin_amdgcn_global_load_lds(
      (__attribute__((address_space(1))) void*)g,
      (__attribute__((address_space(3))) void*)l, 16, 0, 0);
}

__global__ void zero_out_k(float* out) {
  const size_t i = ((size_t)blockIdx.x * 256 + threadIdx.x) * 4;
  *(float4*)(out + i) = make_float4(0.f, 0.f, 0.f, 0.f);
}

__global__ void init_k(int* cnt) {
  if (threadIdx.x < NEXP) cnt[threadIdx.x] = 0;
}

__global__ void router_k(const float* __restrict__ x, const float* __restrict__ gw,
                         __hip_bfloat16* __restrict__ xb, int* __restrict__ cnt,
                         int* __restrict__ elist, float* __restrict__ ewts) {
  const int n = blockIdx.x;
  const int t = threadIdx.x;
  const float* xr = x + (size_t)n * DIM;
  const float4 v0 = *(const float4*)(xr + t * 8);
  const float4 v1 = *(const float4*)(xr + t * 8 + 4);
  uint4 u;
  u.x = pkbf(v0.x, v0.y); u.y = pkbf(v0.z, v0.w);
  u.z = pkbf(v1.x, v1.y); u.w = pkbf(v1.z, v1.w);
  *(uint4*)(xb + (size_t)n * DIM + t * 8) = u;

  float p[NEXP];
#pragma unroll
  for (int e = 0; e < NEXP; ++e) {
    const float* g = gw + e * DIM + t * 8;
    const float4 g0 = *(const float4*)g;
    const float4 g1 = *(const float4*)(g + 4);
    p[e] = v0.x * g0.x + v0.y * g0.y + v0.z * g0.z + v0.w * g0.w +
           v1.x * g1.x + v1.y * g1.y + v1.z * g1.z + v1.w * g1.w;
  }
#pragma unroll
  for (int off = 32; off >= 1; off >>= 1)
#pragma unroll
    for (int e = 0; e < NEXP; ++e) p[e] += __shfl_xor(p[e], off, 64);

  __shared__ float red[4][NEXP];
  const int lane = t & 63, wv = t >> 6;
  if (lane == 0) {
#pragma unroll
    for (int e = 0; e < NEXP; ++e) red[wv][e] = p[e];
  }
  __syncthreads();
  if (t == 0) {
    float l0 = -1e30f, l1 = -1e30f;
    int e0 = 0, e1 = 0;
#pragma unroll
    for (int e = 0; e < NEXP; ++e) {
      float v = red[0][e] + red[1][e] + red[2][e] + red[3][e];
      if (v > l0) { l1 = l0; e1 = e0; l0 = v; e0 = e; }
      else if (v > l1) { l1 = v; e1 = e; }
    }
    const float ed = expf(l1 - l0);
    const float inv = 1.f / (1.f + ed);
    int s0 = atomicAdd(cnt + e0, 1);
    elist[e0 * N_TOK + s0] = n;
    ewts[e0 * N_TOK + s0] = inv;
    int s1 = atomicAdd(cnt + e1, 1);
    elist[e1 * N_TOK + s1] = (int)((uint32_t)n | 0x80000000u);
    ewts[e1 * N_TOK + s1] = ed * inv;
  }
}

__global__ void scan_k(const int* __restrict__ cnt, int* __restrict__ ebase) {
  if (threadIdx.x == 0 && blockIdx.x == 0) {
    int b = 0;
    for (int e = 0; e < NEXP; ++e) { ebase[e] = b; b += (cnt[e] + 255) & ~255; }
  }
}

// ============================================================================
// 256x256 grouped GEMM, BK=64, 8 waves, 4 phases/K-tile, deep pipeline:
//   A(t+1): 4x gld16 at t.p0 (pre-swizzled global src, linear LDS)  [4-ph lead]
//   B_h0(t+2): 4x global_load f32 at t.p0 -> cvt+swz ds_write at (t+1).p0
//   B_h1(t+2): same at p1.  All deadlines enforced by vmcnt(8), never 0.
// LDS per buf 64KB: A [256][64]bf16 @0, B [256][64]bf16 @32768; 2 bufs.
// Swizzle: granule' = g ^ (row&7)  (byte ^= (row&7)<<4), both sides.
// ============================================================================
template <int KD, int MODE>
__global__ __launch_bounds__(512, 2) void gemm256(
    const __hip_bfloat16* __restrict__ Asrc, const float* __restrict__ Bsrc,
    __hip_bfloat16* __restrict__ Gh, float* __restrict__ out,
    const int* __restrict__ cnt, const int* __restrict__ ebase,
    const int* __restrict__ elist, const float* __restrict__ ewts) {
  constexpr int NT = KD / 64;
  constexpr int NROWS = (MODE == 2 ? DIM : FDIM);
  const int e = blockIdx.z;
  const int count = cnt[e];
  const int mt = blockIdx.y;
  if (mt * BMN >= count) return;
  const int nt = blockIdx.x;
  const int n0 = nt * BMN;

  __shared__ char lds[131072];

  const int tid = threadIdx.x;
  const int lane = tid & 63, wv = tid >> 6;
  const int wr = wv >> 2, wc = wv & 3;
  const int* lst = elist + e * N_TOK;
  const size_t hrow0 = (size_t)ebase[e] + (size_t)mt * BMN;

  // ---- A staging: 4 gld16/thread/tile (proven round-2 addressing)
  const int g_srcA = (lane & 7) ^ (lane >> 3);
  size_t srcAoff[2][2];
  int ldsAoff[2][2];
#pragma unroll
  for (int hf = 0; hf < 2; ++hf)
#pragma unroll
    for (int i = 0; i < 2; ++i) {
      const int r = hf * 128 + (2 * wv + i) * 8 + (lane >> 3);
      size_t grow;
      if (MODE == 2) {
        grow = hrow0 + r;
      } else {
        int idx = mt * BMN + r;
        if (idx >= count) idx = 0;
        grow = (size_t)(lst[idx] & 0x7fffffff);
      }
      srcAoff[hf][i] = grow * (size_t)KD + g_srcA * 8;
      ldsAoff[hf][i] = hf * 16384 + (2 * wv + i) * 1024;
    }

  // ---- B reg staging: thread covers row rb, granules gp,gp+1 of each half
  const int rb = tid >> 2, gp = (tid & 3) * 2;
  const float* qB[2];
  int wB[2][2];
#pragma unroll
  for (int hf = 0; hf < 2; ++hf) {
    qB[hf] = Bsrc + ((size_t)e * NROWS + n0 + hf * 128 + rb) * (size_t)KD + gp * 8;
    const int base = 32768 + (hf * 128 + rb) * 128;
    wB[hf][0] = base + ((gp ^ (rb & 7)) << 4);
    wB[hf][1] = base + (((gp + 1) ^ (rb & 7)) << 4);
  }

  // ---- fragment read offsets (proven round-2)
  int frag_off[2];
#pragma unroll
  for (int h = 0; h < 2; ++h)
    frag_off[h] = (lane & 15) * 128 + (((h * 4 + (lane >> 4)) ^ (lane & 7)) << 4);
  const int ardb = wr * 16384;
  const int brd = 32768 + wc * 8192;

  f32x4 acc[8][4];
#pragma unroll
  for (int m = 0; m < 8; ++m)
#pragma unroll
    for (int n = 0; n < 4; ++n) acc[m][n] = {0.f, 0.f, 0.f, 0.f};
  s16x8 Afr[4], Bfr[2][4];
  float4 ql0[4], ql1[4];

  auto stageA = [&](int tt, int dbuf) {
#pragma unroll
    for (int hf = 0; hf < 2; ++hf)
#pragma unroll
      for (int i = 0; i < 2; ++i)
        gld16(Asrc + srcAoff[hf][i] + tt * 64, lds + dbuf * 65536 + ldsAoff[hf][i]);
  };
  auto loadB0 = [&](int tt) {
    ql0[0] = *(const float4*)(qB[0] + tt * 64);
    ql0[1] = *(const float4*)(qB[0] + tt * 64 + 4);
    ql0[2] = *(const float4*)(qB[0] + tt * 64 + 8);
    ql0[3] = *(const float4*)(qB[0] + tt * 64 + 12);
  };
  auto loadB1 = [&](int tt) {
    ql1[0] = *(const float4*)(qB[1] + tt * 64);
    ql1[1] = *(const float4*)(qB[1] + tt * 64 + 4);
    ql1[2] = *(const float4*)(qB[1] + tt * 64 + 8);
    ql1[3] = *(const float4*)(qB[1] + tt * 64 + 12);
  };
  auto writeB0 = [&](int dbuf) {
    uint4 u;
    u.x = pkbf(ql0[0].x, ql0[0].y); u.y = pkbf(ql0[0].z, ql0[0].w);
    u.z = pkbf(ql0[1].x, ql0[1].y); u.w = pkbf(ql0[1].z, ql0[1].w);
    *(uint4*)(lds + dbuf * 65536 + wB[0][0]) = u;
    u.x = pkbf(ql0[2].x, ql0[2].y); u.y = pkbf(ql0[2].z, ql0[2].w);
    u.z = pkbf(ql0[3].x, ql0[3].y); u.w = pkbf(ql0[3].z, ql0[3].w);
    *(uint4*)(lds + dbuf * 65536 + wB[0][1]) = u;
  };
  auto writeB1 = [&](int dbuf) {
    uint4 u;
    u.x = pkbf(ql1[0].x, ql1[0].y); u.y = pkbf(ql1[0].z, ql1[0].w);
    u.z = pkbf(ql1[1].x, ql1[1].y); u.w = pkbf(ql1[1].z, ql1[1].w);
    *(uint4*)(lds + dbuf * 65536 + wB[1][0]) = u;
    u.x = pkbf(ql1[2].x, ql1[2].y); u.y = pkbf(ql1[2].z, ql1[2].w);
    u.z = pkbf(ql1[3].x, ql1[3].y); u.w = pkbf(ql1[3].z, ql1[3].w);
    *(uint4*)(lds + dbuf * 65536 + wB[1][1]) = u;
  };
  auto rdA = [&](int dbuf, int mb, int h) {
#pragma unroll
    for (int s = 0; s < 4; ++s)
      Afr[s] = *(const s16x8*)(lds + dbuf * 65536 + ardb + (mb + s) * 2048 + frag_off[h]);
  };
  auto rdB = [&](int dbuf, int h) {
#pragma unroll
    for (int n = 0; n < 4; ++n)
      Bfr[h][n] = *(const s16x8*)(lds + dbuf * 65536 + brd + n * 2048 + frag_off[h]);
  };

#define PH_PRE()                                            \
  __builtin_amdgcn_sched_barrier(0);                        \
  __builtin_amdgcn_s_barrier();                             \
  __builtin_amdgcn_sched_barrier(0);                        \
  asm volatile("s_waitcnt lgkmcnt(0)" ::: "memory");        \
  __builtin_amdgcn_sched_barrier(0);                        \
  __builtin_amdgcn_s_setprio(1);

#define PH_POST()                                           \
  __builtin_amdgcn_s_setprio(0);                            \
  __builtin_amdgcn_sched_barrier(0);                        \
  __builtin_amdgcn_s_barrier();                             \
  __builtin_amdgcn_sched_barrier(0);

#define VM8()  asm volatile("s_waitcnt vmcnt(8)" ::: "memory")
#define VM4()  asm volatile("s_waitcnt vmcnt(4)" ::: "memory")
#define VM0()  asm volatile("s_waitcnt vmcnt(0)" ::: "memory")

#define MFMA16(MB, H)                                                     \
  _Pragma("unroll") for (int s = 0; s < 4; ++s)                           \
  _Pragma("unroll") for (int n = 0; n < 4; ++n)                           \
    acc[(MB) + s][n] = __builtin_amdgcn_mfma_f32_16x16x32_bf16(           \
        Afr[s], Bfr[H][n], acc[(MB) + s][n], 0, 0, 0);

  // ---- prologue: B(0)->buf0 (via regs); A(0)->buf0; preload B(1) regs
  loadB0(0); loadB1(0);
  VM4(); writeB0(0);
  VM0(); writeB1(0);
  stageA(0, 0);                 // oldest outstanding entering loop
  loadB0(1); loadB1(1);
  asm volatile("s_waitcnt lgkmcnt(0)" ::: "memory");
  __builtin_amdgcn_sched_barrier(0);
  __builtin_amdgcn_s_barrier();
  __builtin_amdgcn_sched_barrier(0);
  // outstanding: A(0)x4, B0(1)x4, B1(1)x4

  for (int t = 0; t < NT; ++t) {
    const int nb = t & 1;
    const int tSA = (t + 1 < NT) ? t + 1 : NT - 1;   // clamp keeps vmcnt uniform
    const int tLB = (t + 2 < NT) ? t + 2 : NT - 1;
    // --- p0: stage A(t+1); retire+write B_h0(t+1); refill B_h0(t+2)
    stageA(tSA, nb ^ 1);
    VM8();                       // drains A(t) + B_h0(t+1)
    writeB0(nb ^ 1);
    loadB0(tLB);
    rdB(nb, 0); rdA(nb, 0, 0);
    PH_PRE(); MFMA16(0, 0); PH_POST();
    // --- p1: retire+write B_h1(t+1); refill B_h1(t+2)
    VM8();                       // drains B_h1(t+1)
    writeB1(nb ^ 1);
    loadB1(tLB);
    rdB(nb, 1); rdA(nb, 0, 1);
    PH_PRE(); MFMA16(0, 1); PH_POST();
    // --- p2
    rdA(nb, 4, 0);
    PH_PRE(); MFMA16(4, 0); PH_POST();
    // --- p3
    rdA(nb, 4, 1);
    PH_PRE(); MFMA16(4, 1); PH_POST();
  }

  // ---- epilogue
  const int erow = (lane >> 4) * 4;
  const int ecol = lane & 15;
  if constexpr (MODE == 0) {
#pragma unroll
    for (int m = 0; m < 8; ++m)
#pragma unroll
      for (int n = 0; n < 4; ++n) {
        const size_t cb = n0 + wc * 64 + n * 16 + ecol;
#pragma unroll
        for (int j = 0; j < 4; ++j) {
          const size_t r = hrow0 + wr * 128 + m * 16 + erow + j;
          Gh[r * FDIM + cb] = __float2bfloat16(acc[m][n][j]);
        }
      }
  } else if constexpr (MODE == 1) {
#pragma unroll
    for (int m = 0; m < 8; ++m)
#pragma unroll
      for (int n = 0; n < 4; ++n) {
        const size_t cb = n0 + wc * 64 + n * 16 + ecol;
#pragma unroll
        for (int j = 0; j < 4; ++j) {
          const size_t r = hrow0 + wr * 128 + m * 16 + erow + j;
          const float g = __bfloat162float(Gh[r * FDIM + cb]);
          const float hv = g / (1.f + __expf(-g)) * acc[m][n][j];
          Gh[r * FDIM + cb] = __float2bfloat16(hv);
        }
      }
  } else {
#pragma unroll
    for (int m = 0; m < 8; ++m)
#pragma unroll
      for (int j = 0; j < 4; ++j) {
        const int i = mt * BMN + wr * 128 + m * 16 + erow + j;
        if (i < count) {
          const uint32_t info = (uint32_t)lst[i];
          const int tok = (int)(info & 0x7fffffffu);
          const float wt = ewts[e * N_TOK + i];
          float* prow = out + (size_t)tok * DIM;
#pragma unroll
          for (int n = 0; n < 4; ++n) {
            const int cb = n0 + wc * 64 + n * 16 + ecol;
            atomicAdd(prow + cb, wt * acc[m][n][j]);
          }
        }
      }
  }
}

extern "C" void kernel_launch(void* const* d_in, const int* in_sizes, int n_in,
                              void* d_out, int out_size, void* d_ws, size_t ws_size,
                              hipStream_t stream) {
  const float* stm = (const float*)d_in[0];
  const float* gw = (const float*)d_in[1];
  const float* w1 = (const float*)d_in[2];
  const float* w2 = (const float*)d_in[3];
  const float* w3 = (const float*)d_in[4];
  float* out = (float*)d_out;
  char* ws = (char*)d_ws;

  __hip_bfloat16* xb = (__hip_bfloat16*)(ws + XB_OFF);
  __hip_bfloat16* Gh = (__hip_bfloat16*)(ws + GH_OFF);
  int* cnt = (int*)(ws + CNT_OFF);
  int* ebase = (int*)(ws + EBASE_OFF);
  int* elist = (int*)(ws + ELIST_OFF);
  float* ewts = (float*)(ws + EWTS_OFF);

  zero_out_k<<<N_TOK * DIM / 1024, 256, 0, stream>>>(out);
  init_k<<<1, 64, 0, stream>>>(cnt);
  router_k<<<N_TOK, 256, 0, stream>>>(stm, gw, xb, cnt, elist, ewts);
  scan_k<<<1, 64, 0, stream>>>(cnt, ebase);

  const dim3 gUp(FDIM / BMN, N_TOK / BMN, NEXP);   // (16, 32, 8)
  const dim3 gDn(DIM / BMN, N_TOK / BMN, NEXP);    // (8, 32, 8)

  gemm256<DIM, 0><<<gUp, 512, 0, stream>>>(xb, w1, Gh, out, cnt, ebase, elist, ewts);
  gemm256<DIM, 1><<<gUp, 512, 0, stream>>>(xb, w3, Gh, out, cnt, ebase, elist, ewts);
  gemm256<FDIM, 2><<<gDn, 512, 0, stream>>>(Gh, w2, Gh, out, cnt, ebase, elist, ewts);
}

// Round 4
// 1673.727 us; speedup vs baseline: 1.1913x; 1.1287x over previous
//
#include <hip/hip_runtime.h>
#include <hip/hip_bf16.h>
#include <stdint.h>

#define N_TOK 8192
#define DIM   2048
#define FDIM  4096
#define NEXP  8
#define BMN   256

// ---- ws layout (bytes) ---- peak use ~252 MB; round-1 proved ws >= 311 MB
#define XB_OFF   0ull                        // bf16 x  [8192][2048]   33,554,432
#define GH_OFF   33554432ull                 // bf16 G/h [18432][4096] 150,994,944
#define META_OFF 184549376ull
#define CNT_OFF   (META_OFF)                 // int[8]
#define EBASE_OFF (META_OFF + 64ull)         // int[8]
#define ELIST_OFF (META_OFF + 128ull)        // int[8][8192]
#define EWTS_OFF  (ELIST_OFF + 262144ull)    // f32[8][8192]
#define WB_OFF   185073920ull                // bf16 weight half-buffer, 67,108,864
// end: 252,182,784

typedef float f32x4 __attribute__((ext_vector_type(4)));
typedef short s16x8 __attribute__((ext_vector_type(8)));

__device__ __forceinline__ uint32_t pkbf(float a, float b) {
  uint32_t ua = __builtin_bit_cast(uint32_t, a) + 0x8000u;
  uint32_t ub = __builtin_bit_cast(uint32_t, b) + 0x8000u;
  return (ua >> 16) | (ub & 0xffff0000u);
}

__device__ __forceinline__ void gld16(const void* g, void* l) {
  __builtin_amdgcn_global_load_lds(
      (__attribute__((address_space(1))) void*)g,
      (__attribute__((address_space(3))) void*)l, 16, 0, 0);
}

__global__ void zero_out_k(float* out) {
  const size_t i = ((size_t)blockIdx.x * 256 + threadIdx.x) * 4;
  *(float4*)(out + i) = make_float4(0.f, 0.f, 0.f, 0.f);
}

__global__ void init_k(int* cnt) {
  if (threadIdx.x < NEXP) cnt[threadIdx.x] = 0;
}

__global__ void router_k(const float* __restrict__ x, const float* __restrict__ gw,
                         __hip_bfloat16* __restrict__ xb, int* __restrict__ cnt,
                         int* __restrict__ elist, float* __restrict__ ewts) {
  const int n = blockIdx.x;
  const int t = threadIdx.x;
  const float* xr = x + (size_t)n * DIM;
  const float4 v0 = *(const float4*)(xr + t * 8);
  const float4 v1 = *(const float4*)(xr + t * 8 + 4);
  uint4 u;
  u.x = pkbf(v0.x, v0.y); u.y = pkbf(v0.z, v0.w);
  u.z = pkbf(v1.x, v1.y); u.w = pkbf(v1.z, v1.w);
  *(uint4*)(xb + (size_t)n * DIM + t * 8) = u;

  float p[NEXP];
#pragma unroll
  for (int e = 0; e < NEXP; ++e) {
    const float* g = gw + e * DIM + t * 8;
    const float4 g0 = *(const float4*)g;
    const float4 g1 = *(const float4*)(g + 4);
    p[e] = v0.x * g0.x + v0.y * g0.y + v0.z * g0.z + v0.w * g0.w +
           v1.x * g1.x + v1.y * g1.y + v1.z * g1.z + v1.w * g1.w;
  }
#pragma unroll
  for (int off = 32; off >= 1; off >>= 1)
#pragma unroll
    for (int e = 0; e < NEXP; ++e) p[e] += __shfl_xor(p[e], off, 64);

  __shared__ float red[4][NEXP];
  const int lane = t & 63, wv = t >> 6;
  if (lane == 0) {
#pragma unroll
    for (int e = 0; e < NEXP; ++e) red[wv][e] = p[e];
  }
  __syncthreads();
  if (t == 0) {
    float l0 = -1e30f, l1 = -1e30f;
    int e0 = 0, e1 = 0;
#pragma unroll
    for (int e = 0; e < NEXP; ++e) {
      float v = red[0][e] + red[1][e] + red[2][e] + red[3][e];
      if (v > l0) { l1 = l0; e1 = e0; l0 = v; e0 = e; }
      else if (v > l1) { l1 = v; e1 = e; }
    }
    const float ed = expf(l1 - l0);
    const float inv = 1.f / (1.f + ed);
    int s0 = atomicAdd(cnt + e0, 1);
    elist[e0 * N_TOK + s0] = n;
    ewts[e0 * N_TOK + s0] = inv;
    int s1 = atomicAdd(cnt + e1, 1);
    elist[e1 * N_TOK + s1] = (int)((uint32_t)n | 0x80000000u);
    ewts[e1 * N_TOK + s1] = ed * inv;
  }
}

__global__ void scan_k(const int* __restrict__ cnt, int* __restrict__ ebase) {
  if (threadIdx.x == 0 && blockIdx.x == 0) {
    int b = 0;
    for (int e = 0; e < NEXP; ++e) { ebase[e] = b; b += (cnt[e] + 255) & ~255; }
  }
}

// convert rows [r0, r0+nrh) of each expert's [rtot][kd] fp32 matrix -> bf16 [e][nrh][kd]
__global__ void convW_k(const float* __restrict__ src, __hip_bfloat16* __restrict__ dst,
                        int r0, int nrh, int rtot, int kd) {
  const int cpr = kd / 8;                       // 8-elem chunks per row
  const int total = NEXP * nrh * cpr;
  for (int i = blockIdx.x * blockDim.x + threadIdx.x; i < total;
       i += gridDim.x * blockDim.x) {
    const int e = i / (nrh * cpr);
    const int rem = i - e * nrh * cpr;
    const int lr = rem / cpr;
    const int c = rem - lr * cpr;
    const float* s = src + ((size_t)e * rtot + r0 + lr) * (size_t)kd + c * 8;
    const float4 a = *(const float4*)s;
    const float4 b = *(const float4*)(s + 4);
    uint4 u;
    u.x = pkbf(a.x, a.y); u.y = pkbf(a.z, a.w);
    u.z = pkbf(b.x, b.y); u.w = pkbf(b.z, b.w);
    *(uint4*)(dst + ((size_t)e * nrh + lr) * (size_t)kd + c * 8) = u;
  }
}

// ============================================================================
// 256x256 grouped GEMM, BK=64, 8 waves, 4 phases/K-tile, both operands bf16
// staged via global_load_lds (pre-swizzled per-lane global source, linear LDS).
// Staging for tile t+1: A (4 gld16) at p0, B (4 gld16) at p1 -> youngest load
// is 3 phases old at the per-tile vmcnt(0) boundary (sources are LLC-resident).
// LDS per dbuf 64KB: A [256][64]bf16 @0, B @32768; 2 dbufs = 128KB.
// Swizzle: LDS row r granule g holds src granule g^(r&7); frag reads XOR back.
// MODE 0: G = Xb@w1^T -> Gh ; MODE 1: h = silu(Gh)*(Xb@w3^T) -> Gh ;
// MODE 2: out += we * (h@w2^T)  (atomicAdd, 2 adds/elem, commutative).
// ============================================================================
template <int KD, int MODE>
__global__ __launch_bounds__(512, 2) void gemm256(
    const __hip_bfloat16* __restrict__ Asrc, const __hip_bfloat16* __restrict__ Bw,
    __hip_bfloat16* __restrict__ Gh, float* __restrict__ out,
    const int* __restrict__ cnt, const int* __restrict__ ebase,
    const int* __restrict__ elist, const float* __restrict__ ewts,
    int ntoff, int noff) {
  constexpr int NT = KD / 64;
  constexpr int NRH = (MODE == 2 ? 1024 : 2048);   // rows per expert in Bw half
  const int e = blockIdx.z;
  const int count = cnt[e];
  const int mt = blockIdx.y;
  if (mt * BMN >= count) return;
  const int n0 = (ntoff + blockIdx.x) * BMN;

  __shared__ char lds[131072];

  const int tid = threadIdx.x;
  const int lane = tid & 63, wv = tid >> 6;
  const int wr = wv >> 2, wc = wv & 3;
  const int* lst = elist + e * N_TOK;
  const size_t hrow0 = (size_t)ebase[e] + (size_t)mt * BMN;

  // ---- staging addresses: per thread 4 A-loads + 4 B-loads per K-tile
  const int gsrc = (lane & 7) ^ (lane >> 3);
  size_t srcA[2][2], srcB[2][2];
  int ldsOff[2][2];
#pragma unroll
  for (int hf = 0; hf < 2; ++hf)
#pragma unroll
    for (int i = 0; i < 2; ++i) {
      const int r = hf * 128 + (2 * wv + i) * 8 + (lane >> 3);
      size_t ga;
      if (MODE == 2) {
        ga = hrow0 + r;
      } else {
        int idx = mt * BMN + r;
        if (idx >= count) idx = 0;
        ga = (size_t)(lst[idx] & 0x7fffffff);
      }
      srcA[hf][i] = ga * (size_t)KD + gsrc * 8;
      srcB[hf][i] = ((size_t)e * NRH + (n0 - noff) + r) * (size_t)KD + gsrc * 8;
      ldsOff[hf][i] = hf * 16384 + (2 * wv + i) * 1024;
    }

  // ---- fragment read offsets
  int frag_off[2];
#pragma unroll
  for (int h = 0; h < 2; ++h)
    frag_off[h] = (lane & 15) * 128 + (((h * 4 + (lane >> 4)) ^ (lane & 7)) << 4);
  const int ardb = wr * 16384;
  const int brd = 32768 + wc * 8192;

  f32x4 acc[8][4];
#pragma unroll
  for (int m = 0; m < 8; ++m)
#pragma unroll
    for (int n = 0; n < 4; ++n) acc[m][n] = {0.f, 0.f, 0.f, 0.f};
  s16x8 Afr[4], Bfr[2][4];

  auto stageA = [&](int tt, int dbuf) {
#pragma unroll
    for (int hf = 0; hf < 2; ++hf)
#pragma unroll
      for (int i = 0; i < 2; ++i)
        gld16(Asrc + srcA[hf][i] + tt * 64, lds + dbuf * 65536 + ldsOff[hf][i]);
  };
  auto stageB = [&](int tt, int dbuf) {
#pragma unroll
    for (int hf = 0; hf < 2; ++hf)
#pragma unroll
      for (int i = 0; i < 2; ++i)
        gld16(Bw + srcB[hf][i] + tt * 64, lds + dbuf * 65536 + 32768 + ldsOff[hf][i]);
  };
  auto rdA = [&](int dbuf, int mb, int h) {
#pragma unroll
    for (int s = 0; s < 4; ++s)
      Afr[s] = *(const s16x8*)(lds + dbuf * 65536 + ardb + (mb + s) * 2048 + frag_off[h]);
  };
  auto rdB = [&](int dbuf, int h) {
#pragma unroll
    for (int n = 0; n < 4; ++n)
      Bfr[h][n] = *(const s16x8*)(lds + dbuf * 65536 + brd + n * 2048 + frag_off[h]);
  };

#define PH_PRE()                                            \
  __builtin_amdgcn_sched_barrier(0);                        \
  __builtin_amdgcn_s_barrier();                             \
  __builtin_amdgcn_sched_barrier(0);                        \
  asm volatile("s_waitcnt lgkmcnt(0)" ::: "memory");        \
  __builtin_amdgcn_sched_barrier(0);                        \
  __builtin_amdgcn_s_setprio(1);

#define PH_POST()                                           \
  __builtin_amdgcn_s_setprio(0);                            \
  __builtin_amdgcn_sched_barrier(0);                        \
  __builtin_amdgcn_s_barrier();                             \
  __builtin_amdgcn_sched_barrier(0);

#define MFMA16(MB, H)                                                     \
  _Pragma("unroll") for (int s = 0; s < 4; ++s)                           \
  _Pragma("unroll") for (int n = 0; n < 4; ++n)                           \
    acc[(MB) + s][n] = __builtin_amdgcn_mfma_f32_16x16x32_bf16(           \
        Afr[s], Bfr[H][n], acc[(MB) + s][n], 0, 0, 0);

  // ---- prologue: stage tile 0 into buf 0, drain, barrier
  stageA(0, 0); stageB(0, 0);
  asm volatile("s_waitcnt vmcnt(0)" ::: "memory");
  __builtin_amdgcn_sched_barrier(0);
  __builtin_amdgcn_s_barrier();
  __builtin_amdgcn_sched_barrier(0);

  for (int t = 0; t < NT; ++t) {
    const int nb = t & 1;
    const int tn = (t + 1 < NT) ? t + 1 : NT - 1;   // clamp: redundant tail reload
    // p0: stage A(t+1); frags B.h0 + A m0-3.h0
    stageA(tn, nb ^ 1);
    rdB(nb, 0); rdA(nb, 0, 0);
    PH_PRE(); MFMA16(0, 0); PH_POST();
    // p1: stage B(t+1); frags B.h1 + A m0-3.h1
    stageB(tn, nb ^ 1);
    rdB(nb, 1); rdA(nb, 0, 1);
    PH_PRE(); MFMA16(0, 1); PH_POST();
    // p2: A m4-7.h0 (Bfr[0] reused)
    rdA(nb, 4, 0);
    PH_PRE(); MFMA16(4, 0); PH_POST();
    // p3: A m4-7.h1; tile-boundary drain
    rdA(nb, 4, 1);
    PH_PRE(); MFMA16(4, 1);
    __builtin_amdgcn_s_setprio(0);
    __builtin_amdgcn_sched_barrier(0);
    asm volatile("s_waitcnt vmcnt(0)" ::: "memory");
    __builtin_amdgcn_sched_barrier(0);
    __builtin_amdgcn_s_barrier();
    __builtin_amdgcn_sched_barrier(0);
  }

  // ---- epilogue
  const int erow = (lane >> 4) * 4;
  const int ecol = lane & 15;
  if constexpr (MODE == 0) {
#pragma unroll
    for (int m = 0; m < 8; ++m)
#pragma unroll
      for (int n = 0; n < 4; ++n) {
        const size_t cb = n0 + wc * 64 + n * 16 + ecol;
#pragma unroll
        for (int j = 0; j < 4; ++j) {
          const size_t r = hrow0 + wr * 128 + m * 16 + erow + j;
          Gh[r * FDIM + cb] = __float2bfloat16(acc[m][n][j]);
        }
      }
  } else if constexpr (MODE == 1) {
#pragma unroll
    for (int m = 0; m < 8; ++m)
#pragma unroll
      for (int n = 0; n < 4; ++n) {
        const size_t cb = n0 + wc * 64 + n * 16 + ecol;
#pragma unroll
        for (int j = 0; j < 4; ++j) {
          const size_t r = hrow0 + wr * 128 + m * 16 + erow + j;
          const float g = __bfloat162float(Gh[r * FDIM + cb]);
          const float hv = g / (1.f + __expf(-g)) * acc[m][n][j];
          Gh[r * FDIM + cb] = __float2bfloat16(hv);
        }
      }
  } else {
#pragma unroll
    for (int m = 0; m < 8; ++m)
#pragma unroll
      for (int j = 0; j < 4; ++j) {
        const int i = mt * BMN + wr * 128 + m * 16 + erow + j;
        if (i < count) {
          const uint32_t info = (uint32_t)lst[i];
          const int tok = (int)(info & 0x7fffffffu);
          const float wt = ewts[e * N_TOK + i];
          float* prow = out + (size_t)tok * DIM;
#pragma unroll
          for (int n = 0; n < 4; ++n) {
            const int cb = n0 + wc * 64 + n * 16 + ecol;
            atomicAdd(prow + cb, wt * acc[m][n][j]);
          }
        }
      }
  }
}

extern "C" void kernel_launch(void* const* d_in, const int* in_sizes, int n_in,
                              void* d_out, int out_size, void* d_ws, size_t ws_size,
                              hipStream_t stream) {
  const float* stm = (const float*)d_in[0];
  const float* gw = (const float*)d_in[1];
  const float* w1 = (const float*)d_in[2];
  const float* w2 = (const float*)d_in[3];
  const float* w3 = (const float*)d_in[4];
  float* out = (float*)d_out;
  char* ws = (char*)d_ws;

  __hip_bfloat16* xb = (__hip_bfloat16*)(ws + XB_OFF);
  __hip_bfloat16* Gh = (__hip_bfloat16*)(ws + GH_OFF);
  int* cnt = (int*)(ws + CNT_OFF);
  int* ebase = (int*)(ws + EBASE_OFF);
  int* elist = (int*)(ws + ELIST_OFF);
  float* ewts = (float*)(ws + EWTS_OFF);
  __hip_bfloat16* wb = (__hip_bfloat16*)(ws + WB_OFF);

  zero_out_k<<<N_TOK * DIM / 1024, 256, 0, stream>>>(out);
  init_k<<<1, 64, 0, stream>>>(cnt);
  router_k<<<N_TOK, 256, 0, stream>>>(stm, gw, xb, cnt, elist, ewts);
  scan_k<<<1, 64, 0, stream>>>(cnt, ebase);

  const dim3 gUp(8, 32, 8);   // 8 N-panels per half
  const dim3 gDn(4, 32, 8);   // 4 N-panels per half

  // gate GEMM (w1), two F-halves
  convW_k<<<2048, 256, 0, stream>>>(w1, wb, 0, 2048, FDIM, DIM);
  gemm256<DIM, 0><<<gUp, 512, 0, stream>>>(xb, wb, Gh, out, cnt, ebase, elist, ewts, 0, 0);
  convW_k<<<2048, 256, 0, stream>>>(w1, wb, 2048, 2048, FDIM, DIM);
  gemm256<DIM, 0><<<gUp, 512, 0, stream>>>(xb, wb, Gh, out, cnt, ebase, elist, ewts, 8, 2048);

  // up GEMM (w3) + silu*mul, two F-halves
  convW_k<<<2048, 256, 0, stream>>>(w3, wb, 0, 2048, FDIM, DIM);
  gemm256<DIM, 1><<<gUp, 512, 0, stream>>>(xb, wb, Gh, out, cnt, ebase, elist, ewts, 0, 0);
  convW_k<<<2048, 256, 0, stream>>>(w3, wb, 2048, 2048, FDIM, DIM);
  gemm256<DIM, 1><<<gUp, 512, 0, stream>>>(xb, wb, Gh, out, cnt, ebase, elist, ewts, 8, 2048);

  // down GEMM (w2), two D-halves
  convW_k<<<2048, 256, 0, stream>>>(w2, wb, 0, 1024, DIM, FDIM);
  gemm256<FDIM, 2><<<gDn, 512, 0, stream>>>(Gh, wb, Gh, out, cnt, ebase, elist, ewts, 0, 0);
  convW_k<<<2048, 256, 0, stream>>>(w2, wb, 1024, 1024, DIM, FDIM);
  gemm256<FDIM, 2><<<gDn, 512, 0, stream>>>(Gh, wb, Gh, out, cnt, ebase, elist, ewts, 4, 1024);
}